// Round 4
// baseline (493.335 us; speedup 1.0000x reference)
//
#include <hip/hip_runtime.h>

#define ROWS    64             // rows per block (B-stream reuse)
#define THREADS 512            // 8 waves/block; 2 blocks/CU (LDS); 4 waves/SIMD
#define BINS    512
#define WORDS   256            // u16-packed: 2 bins per u32 word
#define LO      (-0.6f)
#define RANGE   (1.3f)

typedef short bf16x8 __attribute__((ext_vector_type(8)));
typedef float f32x4  __attribute__((ext_vector_type(4)));

// fp32 -> bf16 with round-to-nearest-even
__device__ __forceinline__ short f2bf(float f) {
    unsigned int u = __builtin_bit_cast(unsigned int, f);
    u = (u + 0x7FFFu + ((u >> 16) & 1u)) >> 16;
    return (short)u;
}

// pre-pass: fp32 X -> bf16 (one float4 per thread)
__global__ __launch_bounds__(256)
void cvt_kernel(const float* __restrict__ X, short* __restrict__ Xb) {
    int i = blockIdx.x * 256 + threadIdx.x;   // 0 .. 2097151
    float4 v = ((const float4*)X)[i];
    short4 s = { f2bf(v.x), f2bf(v.y), f2bf(v.z), f2bf(v.w) };
    ((short4*)Xb)[i] = s;
}

// NOTE: all loads are plain C++ (no asm, no manual vmcnt). At 4 waves/SIMD,
// TLP hides load latency; compiler-tracked waitcnt is correct under ANY
// remat/spill decision (R3 failed because an asm-load destination was
// spilled before the in-flight load wrote it).
__device__ __forceinline__ void load8(bf16x8* dst, const short* p) {
    #pragma unroll
    for (int ks = 0; ks < 8; ++ks) dst[ks] = *(const bf16x8*)(p + ks * 32);
}

__global__ __launch_bounds__(THREADS, 4)   // 4 waves/EU; VGPR cap 128
void scpp_kernel(const short* __restrict__ X, float* __restrict__ out) {
    const int t    = threadIdx.x;
    const int wave = t >> 6;           // 0..7
    const int lane = t & 63;
    const int q    = lane >> 4;        // quad 0..3
    const int ln   = lane & 15;
    const int rg   = wave & 1;         // row-group: rows m0 + rg*32 .. +31
    const int cg   = wave >> 1;        // col-group: cols nt*64 + cg*16 .. +15
    const int bid  = blockIdx.x;       // 0..511 -> 2 blocks/CU, all resident
    // XCD-batch pinning: blockIdx%8 -> XCD; batch slice resident in XCD L2.
    const int batch = bid & 7;
    const int m0    = (bid >> 3) * ROWS;
    const short* Xb = X + (size_t)batch * 4096 * 256;

    __shared__ unsigned int hist[ROWS * WORDS];  // 64 KB; 2 blocks/CU = 128 KB

    // zero histograms: 16384 words / 512 threads
    #pragma unroll
    for (int i = 0; i < (ROWS * WORDS) / THREADS; ++i)
        hist[t + THREADS * i] = 0u;

    // A fragments: 2 strips of 16 rows = 64 VGPR (the size the RA holds).
    bf16x8 af[2][8];
    {
        #pragma unroll
        for (int s = 0; s < 2; ++s) {
            const short* ap = Xb + (size_t)(m0 + rg * 32 + s * 16 + ln) * 256 + q * 8;
            #pragma unroll
            for (int ks = 0; ks < 8; ++ks)
                af[s][ks] = *(const bf16x8*)(ap + ks * 32);
        }
        #pragma unroll
        for (int s = 0; s < 2; ++s)
            #pragma unroll
            for (int ks = 0; ks < 8; ++ks)
                asm volatile("" : "+v"(af[s][ks]));   // opaque: blocks remat
    }
    __syncthreads();   // hist zeros visible before atomics

    // bin transform: b = (v/256 - LO) * BINS/RANGE == v*scale + off
    const float scale = ((float)BINS / RANGE) / 256.0f;
    const float off   = -LO * ((float)BINS / RANGE);

    auto bins = [&](const f32x4& a, int rowbase) {
        #pragma unroll
        for (int reg = 0; reg < 4; ++reg) {
            int row = rowbase + 4 * q + reg;
            int b = (int)(a[reg] * scale + off);
            b = b < 0 ? 0 : (b > BINS - 1 ? BINS - 1 : b);
            int pw = (b >> 1) ^ ((row * 9) & 31);
            atomicAdd(&hist[row * WORDS + pw], 1u << ((b & 1) * 16));
        }
    };

    auto compute = [&](const bf16x8* bb) {
        f32x4 acc0 = {0.f, 0.f, 0.f, 0.f};
        f32x4 acc1 = {0.f, 0.f, 0.f, 0.f};
        #pragma unroll
        for (int ks = 0; ks < 8; ++ks) {
            acc0 = __builtin_amdgcn_mfma_f32_16x16x32_bf16(af[0][ks], bb[ks], acc0, 0, 0, 0);
            acc1 = __builtin_amdgcn_mfma_f32_16x16x32_bf16(af[1][ks], bb[ks], acc1, 0, 0, 0);
        }
        bins(acc0, rg * 32);
        bins(acc1, rg * 32 + 16);
    };

    // wave's B cols: nt*64 + cg*16 + ln, nt = 0..63
    const short* bp  = Xb + (size_t)(cg * 16 + ln) * 256 + q * 8;
    const size_t NTS = (size_t)64 * 256;   // per-nt col stride in shorts

    // simple C++ ping-pong; compiler schedules loads/waits (correct by
    // construction). TLP across 16 waves/CU provides the latency hiding.
    bf16x8 b0[8], b1[8];
    load8(b0, bp);
    for (int nt = 0; nt < 64; nt += 2) {
        load8(b1, bp + (size_t)(nt + 1) * NTS);
        compute(b0);
        if (nt + 2 < 64)
            load8(b0, bp + (size_t)(nt + 2) * NTS);
        compute(b1);
    }
    __syncthreads();

    // epilogue, in-register per wave: rows 8w .. 8w+7
    const float binw = RANGE / (float)BINS;
    #pragma unroll
    for (int rr = 0; rr < 8; ++rr) {
        const int r = wave * 8 + rr;
        const unsigned int msk = (unsigned int)(r * 9) & 31u;
        const unsigned int* H = &hist[r * WORDS];
        // lane L holds logical words 4L..4L+3 = bins 8L..8L+7 (un-swizzle on read)
        int c[8];
        #pragma unroll
        for (int i2 = 0; i2 < 4; ++i2) {
            unsigned int wd = H[(unsigned int)(4 * lane + i2) ^ msk];
            c[2 * i2]     = (int)(wd & 0xFFFFu);
            c[2 * i2 + 1] = (int)(wd >> 16);
        }
        int local = 0;
        #pragma unroll
        for (int u = 0; u < 8; ++u) local += c[u];
        // suffix-sum over lanes
        int suf = local;
        #pragma unroll
        for (int o2 = 1; o2 < 64; o2 <<= 1) {
            int o = __shfl_down(suf, o2, 64);
            if (lane + o2 < 64) suf += o;
        }
        int run = suf - local;
        int s[8];                         // s[u] = S[8*lane + u] = #values >= bin edge
        #pragma unroll
        for (int u = 7; u >= 0; --u) { run += c[u]; s[u] = run; }

        // answer 256 queries for this row: lane handles i = qq*64 + lane
        #pragma unroll
        for (int qq = 0; qq < 4; ++qq) {
            int i = qq * 64 + lane;
            float rv = 1.0f + (float)i * (4094.0f / 255.0f);
            int k = (int)rintf(rv) + 1;   // k-th largest, k in [2, 4096]
            // binary search over lanes for last L with S[8L] >= k  (S[0]=4096>=k)
            int Lo = 0;
            #pragma unroll
            for (int st = 32; st >= 1; st >>= 1) {
                int cand = Lo + st;       // always <= 63
                int v = __shfl(s[0], cand, 64);
                if (v >= k) Lo = cand;
            }
            // within lane Lo's 8 bins: j_off = #{u: S[8Lo+u] >= k} - 1
            int j8 = 0;
            #pragma unroll
            for (int u = 0; u < 8; ++u) {
                int v = __shfl(s[u], Lo, 64);
                j8 += (v >= k) ? 1 : 0;
            }
            int j = 8 * Lo + j8 - 1;
            out[(size_t)(batch * 4096 + m0 + r) * 256 + i] = LO + ((float)j + 0.5f) * binw;
        }
    }
}

extern "C" void kernel_launch(void* const* d_in, const int* in_sizes, int n_in,
                              void* d_out, int out_size, void* d_ws, size_t ws_size,
                              hipStream_t stream) {
    const float* x = (const float*)d_in[0];
    float* out = (float*)d_out;
    const size_t nelem = (size_t)8 * 4096 * 256;          // 8,388,608
    short* xb = (short*)d_ws;
    hipLaunchKernelGGL(cvt_kernel, dim3(nelem / 1024), dim3(256), 0, stream, x, xb);
    hipLaunchKernelGGL(scpp_kernel, dim3(512), dim3(THREADS), 0, stream, xb, out);
}

// Round 5
// 334.999 us; speedup vs baseline: 1.4726x; 1.4726x over previous
//
#include <hip/hip_runtime.h>

#define ROWS    64             // rows per block (B-stream reuse)
#define THREADS 512            // 8 waves/block; 2 blocks/CU; 4 waves/SIMD
#define BINS    512
#define WORDS   128            // u8-packed: 4 bins per u32 word -> 32 KB hist
#define LO      (-0.6f)
#define RANGE   (1.3f)

typedef short bf16x8 __attribute__((ext_vector_type(8)));
typedef float f32x4  __attribute__((ext_vector_type(4)));

// fp32 -> bf16 with round-to-nearest-even
__device__ __forceinline__ short f2bf(float f) {
    unsigned int u = __builtin_bit_cast(unsigned int, f);
    u = (u + 0x7FFFu + ((u >> 16) & 1u)) >> 16;
    return (short)u;
}

// pre-pass: fp32 X -> bf16 (one float4 per thread)
__global__ __launch_bounds__(256)
void cvt_kernel(const float* __restrict__ X, short* __restrict__ Xb) {
    int i = blockIdx.x * 256 + threadIdx.x;   // 0 .. 2097151
    float4 v = ((const float4*)X)[i];
    short4 s = { f2bf(v.x), f2bf(v.y), f2bf(v.z), f2bf(v.w) };
    ((short4*)Xb)[i] = s;
}

// Register-budget discipline (R3/R4 lessons): per-wave live set must fit the
// 128-VGPR cap with margin. af[2][8]=64 + bb[4]=16 + acc 8 + addr ~15 ≈ 105.
// All loads plain C++ (compiler-tracked waitcnt correct under any RA choice).
__global__ __launch_bounds__(THREADS, 4)   // 4 waves/EU -> 2 blocks/CU, cap 128
void scpp_kernel(const short* __restrict__ X, float* __restrict__ out) {
    const int t    = threadIdx.x;
    const int wave = t >> 6;           // 0..7
    const int lane = t & 63;
    const int q    = lane >> 4;        // quad 0..3
    const int ln   = lane & 15;
    const int rg   = wave & 1;         // row-group: rows m0 + rg*32 .. +31
    const int cg   = wave >> 1;        // col-group: cols nt*64 + cg*16 .. +15
    const int bid  = blockIdx.x;       // 0..511 -> 2 blocks/CU, all resident
    // XCD-batch pinning: blockIdx%8 -> XCD; batch slice resident in XCD L2.
    const int batch = bid & 7;
    const int m0    = (bid >> 3) * ROWS;
    const short* Xb = X + (size_t)batch * 4096 * 256;

    __shared__ unsigned int hist[ROWS * WORDS];  // 32 KB; 2 blocks/CU = 64 KB

    // zero histograms: 8192 words / 512 threads
    #pragma unroll
    for (int i = 0; i < (ROWS * WORDS) / THREADS; ++i)
        hist[t + THREADS * i] = 0u;

    // A fragments: 2 strips of 16 rows = 64 VGPR (shape proven held in R0/R1).
    bf16x8 af[2][8];
    {
        #pragma unroll
        for (int s = 0; s < 2; ++s) {
            const short* ap = Xb + (size_t)(m0 + rg * 32 + s * 16 + ln) * 256 + q * 8;
            #pragma unroll
            for (int ks = 0; ks < 8; ++ks)
                af[s][ks] = *(const bf16x8*)(ap + ks * 32);
        }
        #pragma unroll
        for (int s = 0; s < 2; ++s)
            #pragma unroll
            for (int ks = 0; ks < 8; ++ks)
                asm volatile("" : "+v"(af[s][ks]));   // opaque: blocks remat
    }
    __syncthreads();   // hist zeros visible before atomics

    // bin transform: b = (v/256 - LO) * BINS/RANGE == v*scale + off
    const float scale = ((float)BINS / RANGE) / 256.0f;
    const float off   = -LO * ((float)BINS / RANGE);

    auto bins = [&](const f32x4& a, int rowbase) {
        #pragma unroll
        for (int reg = 0; reg < 4; ++reg) {
            int row = rowbase + 4 * q + reg;
            int b = (int)(a[reg] * scale + off);
            b = b < 0 ? 0 : (b > BINS - 1 ? BINS - 1 : b);
            int pw = (b >> 2) ^ ((row * 9) & 31);           // u8: word = bin>>2
            atomicAdd(&hist[row * WORDS + pw], 1u << ((b & 3) * 8));
        }
    };

    // wave's B cols: nt*64 + cg*16 + ln, nt = 0..63
    const short* bp  = Xb + (size_t)(cg * 16 + ln) * 256 + q * 8;
    const size_t NTS = (size_t)64 * 256;   // per-nt col stride in shorts

    // single-buffered B in 4-fragment halves (16 VGPR live). TLP across
    // 16 waves/CU hides the load latency; no manual pipelining.
    for (int nt = 0; nt < 64; ++nt) {
        const short* p = bp + (size_t)nt * NTS;
        f32x4 acc0 = {0.f, 0.f, 0.f, 0.f};
        f32x4 acc1 = {0.f, 0.f, 0.f, 0.f};
        #pragma unroll
        for (int h = 0; h < 2; ++h) {
            bf16x8 bb[4];
            #pragma unroll
            for (int j = 0; j < 4; ++j)
                bb[j] = *(const bf16x8*)(p + (4 * h + j) * 32);
            #pragma unroll
            for (int j = 0; j < 4; ++j) {
                acc0 = __builtin_amdgcn_mfma_f32_16x16x32_bf16(af[0][4 * h + j], bb[j], acc0, 0, 0, 0);
                acc1 = __builtin_amdgcn_mfma_f32_16x16x32_bf16(af[1][4 * h + j], bb[j], acc1, 0, 0, 0);
            }
        }
        bins(acc0, rg * 32);
        bins(acc1, rg * 32 + 16);
    }
    __syncthreads();

    // epilogue, in-register per wave: rows 8w .. 8w+7
    const float binw = RANGE / (float)BINS;
    #pragma unroll
    for (int rr = 0; rr < 8; ++rr) {
        const int r = wave * 8 + rr;
        const unsigned int msk = (unsigned int)(r * 9) & 31u;
        const unsigned int* H = &hist[r * WORDS];
        // lane L holds logical words 2L..2L+1 = bins 8L..8L+7 (un-swizzle on read)
        int c[8];
        #pragma unroll
        for (int i2 = 0; i2 < 2; ++i2) {
            unsigned int wd = H[(unsigned int)(2 * lane + i2) ^ msk];
            c[4 * i2 + 0] = (int)(wd & 0xFFu);
            c[4 * i2 + 1] = (int)((wd >> 8)  & 0xFFu);
            c[4 * i2 + 2] = (int)((wd >> 16) & 0xFFu);
            c[4 * i2 + 3] = (int)((wd >> 24) & 0xFFu);
        }
        int local = 0;
        #pragma unroll
        for (int u = 0; u < 8; ++u) local += c[u];
        // suffix-sum over lanes
        int suf = local;
        #pragma unroll
        for (int o2 = 1; o2 < 64; o2 <<= 1) {
            int o = __shfl_down(suf, o2, 64);
            if (lane + o2 < 64) suf += o;
        }
        int run = suf - local;
        int s[8];                         // s[u] = S[8*lane + u] = #values >= bin edge
        #pragma unroll
        for (int u = 7; u >= 0; --u) { run += c[u]; s[u] = run; }

        // answer 256 queries for this row: lane handles i = qq*64 + lane
        #pragma unroll
        for (int qq = 0; qq < 4; ++qq) {
            int i = qq * 64 + lane;
            float rv = 1.0f + (float)i * (4094.0f / 255.0f);
            int k = (int)rintf(rv) + 1;   // k-th largest, k in [2, 4096]
            // binary search over lanes for last L with S[8L] >= k  (S[0]=4096>=k)
            int Lo = 0;
            #pragma unroll
            for (int st = 32; st >= 1; st >>= 1) {
                int cand = Lo + st;       // always <= 63
                int v = __shfl(s[0], cand, 64);
                if (v >= k) Lo = cand;
            }
            // within lane Lo's 8 bins: j_off = #{u: S[8Lo+u] >= k} - 1
            int j8 = 0;
            #pragma unroll
            for (int u = 0; u < 8; ++u) {
                int v = __shfl(s[u], Lo, 64);
                j8 += (v >= k) ? 1 : 0;
            }
            int j = 8 * Lo + j8 - 1;
            out[(size_t)(batch * 4096 + m0 + r) * 256 + i] = LO + ((float)j + 0.5f) * binw;
        }
    }
}

extern "C" void kernel_launch(void* const* d_in, const int* in_sizes, int n_in,
                              void* d_out, int out_size, void* d_ws, size_t ws_size,
                              hipStream_t stream) {
    const float* x = (const float*)d_in[0];
    float* out = (float*)d_out;
    const size_t nelem = (size_t)8 * 4096 * 256;          // 8,388,608
    short* xb = (short*)d_ws;
    hipLaunchKernelGGL(cvt_kernel, dim3(nelem / 1024), dim3(256), 0, stream, x, xb);
    hipLaunchKernelGGL(scpp_kernel, dim3(512), dim3(THREADS), 0, stream, xb, out);
}

// Round 6
// 230.412 us; speedup vs baseline: 2.1411x; 1.4539x over previous
//
#include <hip/hip_runtime.h>

#define ROWS    64             // rows per block; 4 strips of 16 per wave (fat ILP)
#define THREADS 256            // 4 waves/block; 2 blocks/CU
#define BINS    512
#define WORDS   256            // u16-packed: 2 bins per u32 word (R5's u8 raised conflicts)
#define LO      (-0.6f)
#define RANGE   (1.3f)

typedef short bf16x8 __attribute__((ext_vector_type(8)));
typedef float f32x4  __attribute__((ext_vector_type(4)));

// fp32 -> bf16 with round-to-nearest-even
__device__ __forceinline__ short f2bf(float f) {
    unsigned int u = __builtin_bit_cast(unsigned int, f);
    u = (u + 0x7FFFu + ((u >> 16) & 1u)) >> 16;
    return (short)u;
}

// pre-pass: fp32 X -> bf16 (one float4 per thread)
__global__ __launch_bounds__(256)
void cvt_kernel(const float* __restrict__ X, short* __restrict__ Xb) {
    int i = blockIdx.x * 256 + threadIdx.x;   // 0 .. 2097151
    float4 v = ((const float4*)X)[i];
    short4 s = { f2bf(v.x), f2bf(v.y), f2bf(v.z), f2bf(v.w) };
    ((short4*)Xb)[i] = s;
}

// Register budget (R2..R5 lessons): cap 256 (launch_bounds(256,2)).
// af[4][8]=128 + bbA/bbB 32 + acc 16 + addr ~15 ≈ 190 < 256 -> af stays in
// real VGPRs (R2's full 64-reg B ping-pong pushed demand to ~280 and forced
// AGPR shuffling of af). All loads plain C++ -- compiler-tracked waitcnt is
// correct under any RA decision (R3/R4: asm-load dests near the cap corrupt
// or catastrophically spill).
__global__ __launch_bounds__(THREADS, 2)
void scpp_kernel(const short* __restrict__ X, float* __restrict__ out) {
    const int t    = threadIdx.x;
    const int wave = t >> 6;           // 0..3  (= col-group)
    const int lane = t & 63;
    const int q    = lane >> 4;        // quad 0..3
    const int ln   = lane & 15;
    const int bid  = blockIdx.x;       // 0..511 -> 2 blocks/CU, all resident
    // XCD-batch pinning: blockIdx%8 -> XCD; batch slice resident in XCD L2.
    const int batch = bid & 7;
    const int m0    = (bid >> 3) * ROWS;
    const short* Xb = X + (size_t)batch * 4096 * 256;

    __shared__ unsigned int hist[ROWS * WORDS];  // 64 KB; 2 blocks/CU = 128 KB

    // zero histograms: 16384 words / 256 threads
    #pragma unroll 4
    for (int i = 0; i < (ROWS * WORDS) / THREADS; ++i)
        hist[t + THREADS * i] = 0u;

    // A fragments: 4 strips of 16 rows = 128 VGPR, held (demand fits cap).
    bf16x8 af[4][8];
    {
        #pragma unroll
        for (int s = 0; s < 4; ++s) {
            const short* ap = Xb + (size_t)(m0 + s * 16 + ln) * 256 + q * 8;
            #pragma unroll
            for (int ks = 0; ks < 8; ++ks)
                af[s][ks] = *(const bf16x8*)(ap + ks * 32);
        }
        #pragma unroll
        for (int s = 0; s < 4; ++s)
            #pragma unroll
            for (int ks = 0; ks < 8; ++ks)
                asm volatile("" : "+v"(af[s][ks]));   // opaque: blocks remat
    }
    __syncthreads();   // hist zeros visible before atomics

    // bin transform: b = (v/256 - LO) * BINS/RANGE == v*scale + off
    const float scale = ((float)BINS / RANGE) / 256.0f;
    const float off   = -LO * ((float)BINS / RANGE);

    auto bins = [&](const f32x4& a, int rowbase) {
        #pragma unroll
        for (int reg = 0; reg < 4; ++reg) {
            int row = rowbase + 4 * q + reg;
            int b = (int)(a[reg] * scale + off);
            b = b < 0 ? 0 : (b > BINS - 1 ? BINS - 1 : b);
            int pw = (b >> 1) ^ ((row * 9) & 31);
            atomicAdd(&hist[row * WORDS + pw], 1u << ((b & 1) * 16));
        }
    };

    // wave's B cols: nt*64 + wave*16 + ln, nt = 0..63
    const short* bp  = Xb + (size_t)(wave * 16 + ln) * 256 + q * 8;
    const size_t NTS = (size_t)64 * 256;   // per-nt col stride in shorts

    // Half-buffer lookahead: bbB (ks 4..7 of nt) loads before computing bbA
    // (ks 0..3), bbA of nt+1 loads before computing bbB. One half always in
    // flight; 8 B-loads feed 32 MFMAs (4 independent chains -> in-wave ILP).
    bf16x8 bbA[4], bbB[4];
    #pragma unroll
    for (int j = 0; j < 4; ++j) bbA[j] = *(const bf16x8*)(bp + j * 32);
    for (int nt = 0; nt < 64; ++nt) {
        const short* p  = bp + (size_t)nt * NTS;
        const short* pn = p + NTS;
        f32x4 acc[4];
        #pragma unroll
        for (int s = 0; s < 4; ++s) acc[s] = f32x4{0.f, 0.f, 0.f, 0.f};

        #pragma unroll
        for (int j = 0; j < 4; ++j) bbB[j] = *(const bf16x8*)(p + (4 + j) * 32);
        #pragma unroll
        for (int j = 0; j < 4; ++j)
            #pragma unroll
            for (int s = 0; s < 4; ++s)
                acc[s] = __builtin_amdgcn_mfma_f32_16x16x32_bf16(af[s][j], bbA[j], acc[s], 0, 0, 0);

        if (nt + 1 < 64) {
            #pragma unroll
            for (int j = 0; j < 4; ++j) bbA[j] = *(const bf16x8*)(pn + j * 32);
        }
        #pragma unroll
        for (int j = 0; j < 4; ++j)
            #pragma unroll
            for (int s = 0; s < 4; ++s)
                acc[s] = __builtin_amdgcn_mfma_f32_16x16x32_bf16(af[s][4 + j], bbB[j], acc[s], 0, 0, 0);

        #pragma unroll
        for (int s = 0; s < 4; ++s) bins(acc[s], s * 16);
    }
    __syncthreads();

    // epilogue, in-register per wave: rows 16w .. 16w+15
    const float binw = RANGE / (float)BINS;
    #pragma unroll
    for (int rr = 0; rr < 16; ++rr) {
        const int r = wave * 16 + rr;
        const unsigned int msk = (unsigned int)(r * 9) & 31u;
        const unsigned int* H = &hist[r * WORDS];
        // lane L holds logical words 4L..4L+3 = bins 8L..8L+7 (un-swizzle on read)
        int c[8];
        #pragma unroll
        for (int i2 = 0; i2 < 4; ++i2) {
            unsigned int wd = H[(unsigned int)(4 * lane + i2) ^ msk];
            c[2 * i2]     = (int)(wd & 0xFFFFu);
            c[2 * i2 + 1] = (int)(wd >> 16);
        }
        int local = 0;
        #pragma unroll
        for (int u = 0; u < 8; ++u) local += c[u];
        // suffix-sum over lanes
        int suf = local;
        #pragma unroll
        for (int o2 = 1; o2 < 64; o2 <<= 1) {
            int o = __shfl_down(suf, o2, 64);
            if (lane + o2 < 64) suf += o;
        }
        int run = suf - local;
        int s[8];                         // s[u] = S[8*lane + u] = #values >= bin edge
        #pragma unroll
        for (int u = 7; u >= 0; --u) { run += c[u]; s[u] = run; }

        // answer 256 queries for this row: lane handles i = qq*64 + lane
        #pragma unroll
        for (int qq = 0; qq < 4; ++qq) {
            int i = qq * 64 + lane;
            float rv = 1.0f + (float)i * (4094.0f / 255.0f);
            int k = (int)rintf(rv) + 1;   // k-th largest, k in [2, 4096]
            // binary search over lanes for last L with S[8L] >= k  (S[0]=4096>=k)
            int Lo = 0;
            #pragma unroll
            for (int st = 32; st >= 1; st >>= 1) {
                int cand = Lo + st;       // always <= 63
                int v = __shfl(s[0], cand, 64);
                if (v >= k) Lo = cand;
            }
            // within lane Lo's 8 bins: j_off = #{u: S[8Lo+u] >= k} - 1
            int j8 = 0;
            #pragma unroll
            for (int u = 0; u < 8; ++u) {
                int v = __shfl(s[u], Lo, 64);
                j8 += (v >= k) ? 1 : 0;
            }
            int j = 8 * Lo + j8 - 1;
            out[(size_t)(batch * 4096 + m0 + r) * 256 + i] = LO + ((float)j + 0.5f) * binw;
        }
    }
}

extern "C" void kernel_launch(void* const* d_in, const int* in_sizes, int n_in,
                              void* d_out, int out_size, void* d_ws, size_t ws_size,
                              hipStream_t stream) {
    const float* x = (const float*)d_in[0];
    float* out = (float*)d_out;
    const size_t nelem = (size_t)8 * 4096 * 256;          // 8,388,608
    short* xb = (short*)d_ws;
    hipLaunchKernelGGL(cvt_kernel, dim3(nelem / 1024), dim3(256), 0, stream, x, xb);
    hipLaunchKernelGGL(scpp_kernel, dim3(512), dim3(THREADS), 0, stream, xb, out);
}

// Round 7
// 228.855 us; speedup vs baseline: 2.1557x; 1.0068x over previous
//
#include <hip/hip_runtime.h>

#define ROWS    64             // rows per block; 4 strips of 16 per wave (fat ILP)
#define THREADS 256            // 4 waves/block; 2 blocks/CU
#define BINS    512
#define WORDS   256            // u16-packed: 2 bins per u32 word
#define LO      (-0.6f)
#define RANGE   (1.3f)

typedef short bf16x8 __attribute__((ext_vector_type(8)));
typedef float f32x4  __attribute__((ext_vector_type(4)));

// fp32 -> bf16 with round-to-nearest-even
__device__ __forceinline__ short f2bf(float f) {
    unsigned int u = __builtin_bit_cast(unsigned int, f);
    u = (u + 0x7FFFu + ((u >> 16) & 1u)) >> 16;
    return (short)u;
}

// pre-pass: fp32 X -> bf16 (one float4 per thread)
__global__ __launch_bounds__(256)
void cvt_kernel(const float* __restrict__ X, short* __restrict__ Xb) {
    int i = blockIdx.x * 256 + threadIdx.x;   // 0 .. 2097151
    float4 v = ((const float4*)X)[i];
    short4 s = { f2bf(v.x), f2bf(v.y), f2bf(v.z), f2bf(v.w) };
    ((short4*)Xb)[i] = s;
}

// Register budget (R2..R6 lessons): af[4][8]=128 lives in AGPRs (unified
// file; R6 VGPR_Count=108 + af alive proves it). Combined demand here:
// 128 AGPR + bb 32 + accE/accO 32 + misc ~30 ≈ 240 <= 256 -> 2 waves/SIMD.
// All loads plain C++ (compiler-tracked waitcnt correct under any RA choice).
__global__ __launch_bounds__(THREADS, 2)
void scpp_kernel(const short* __restrict__ X, float* __restrict__ out) {
    const int t    = threadIdx.x;
    const int wave = t >> 6;           // 0..3  (= col-group)
    const int lane = t & 63;
    const int q    = lane >> 4;        // quad 0..3
    const int ln   = lane & 15;
    const int bid  = blockIdx.x;       // 0..511 -> 2 blocks/CU, all resident
    // XCD-batch pinning: blockIdx%8 -> XCD; batch slice resident in XCD L2.
    const int batch = bid & 7;
    const int m0    = (bid >> 3) * ROWS;
    const short* Xb = X + (size_t)batch * 4096 * 256;

    __shared__ unsigned int hist[ROWS * WORDS];  // 64 KB; 2 blocks/CU = 128 KB

    // zero histograms: 16384 words / 256 threads
    #pragma unroll 4
    for (int i = 0; i < (ROWS * WORDS) / THREADS; ++i)
        hist[t + THREADS * i] = 0u;

    // A fragments: 4 strips of 16 rows = 128 regs (AGPR-resident in the loop).
    bf16x8 af[4][8];
    {
        #pragma unroll
        for (int s = 0; s < 4; ++s) {
            const short* ap = Xb + (size_t)(m0 + s * 16 + ln) * 256 + q * 8;
            #pragma unroll
            for (int ks = 0; ks < 8; ++ks)
                af[s][ks] = *(const bf16x8*)(ap + ks * 32);
        }
        #pragma unroll
        for (int s = 0; s < 4; ++s)
            #pragma unroll
            for (int ks = 0; ks < 8; ++ks)
                asm volatile("" : "+v"(af[s][ks]));   // opaque: blocks remat
    }
    __syncthreads();   // hist zeros visible before atomics

    // bin transform: b = (v/256 - LO) * BINS/RANGE == v*scale + off
    const float scale = ((float)BINS / RANGE) / 256.0f;
    const float off   = -LO * ((float)BINS / RANGE);

    // 2 strips per call (8 elements): fmed3 clamp (1 op vs max+min),
    // cndmask increment select.
    auto bins2 = [&](const f32x4* acc, int sbase) {
        #pragma unroll
        for (int s2 = 0; s2 < 2; ++s2) {
            const f32x4& a = acc[sbase + s2];
            #pragma unroll
            for (int reg = 0; reg < 4; ++reg) {
                int row = (sbase + s2) * 16 + 4 * q + reg;
                float fb = __builtin_amdgcn_fmed3f(a[reg] * scale + off, 0.0f, 511.0f);
                int b = (int)fb;
                int pw = (b >> 1) ^ ((row * 9) & 31);
                unsigned inc = (b & 1) ? 0x10000u : 1u;
                atomicAdd(&hist[row * WORDS + pw], inc);
            }
        }
    };

    // wave's B cols: ntx*64 + wave*16 + ln; per-wave nt ROTATION de-phases
    // the 8 waves/CU on L2 and the DS pipe.
    const short* bp  = Xb + (size_t)(wave * 16 + ln) * 256 + q * 8;
    const size_t NTS = (size_t)64 * 256;   // per-nt col stride in shorts
    auto ptr = [&](int nt) { return bp + (size_t)((nt + (wave << 4)) & 63) * NTS; };

    bf16x8 bbA[4], bbB[4];
    auto loadH = [&](bf16x8* bb, const short* p, int h) {
        #pragma unroll
        for (int j = 0; j < 4; ++j) bb[j] = *(const bf16x8*)(p + (4 * h + j) * 32);
    };
    auto mfmaH = [&](f32x4* acc, const bf16x8* bb, int h) {
        __builtin_amdgcn_s_setprio(1);
        #pragma unroll
        for (int j = 0; j < 4; ++j)
            #pragma unroll
            for (int s = 0; s < 4; ++s)
                acc[s] = __builtin_amdgcn_mfma_f32_16x16x32_bf16(af[s][4 * h + j], bb[j], acc[s], 0, 0, 0);
        __builtin_amdgcn_s_setprio(0);
    };
    auto zero4 = [&](f32x4* acc) {
        #pragma unroll
        for (int s = 0; s < 4; ++s) acc[s] = f32x4{0.f, 0.f, 0.f, 0.f};
    };

    // T15 deferred-bins pipeline: bins(nt-1) executes BETWEEN the MFMA
    // half-clusters of nt -> MFMA pipe and VALU/DS pipe both live in one
    // wave with no dependency. Even/odd acc naming keeps all indexing
    // compile-time (rule #20). Loads at ptr(64)==ptr(0) are harmless.
    f32x4 accE[4], accO[4];

    // peel nt=0 -> accE; advance loads to nt=1
    loadH(bbA, ptr(0), 0);
    loadH(bbB, ptr(0), 1);
    zero4(accE);
    mfmaH(accE, bbA, 0);  loadH(bbA, ptr(1), 0);
    mfmaH(accE, bbB, 1);  loadH(bbB, ptr(1), 1);

    for (int nt = 1; nt < 63; nt += 2) {
        zero4(accO);                                     // MFMA nt   -> accO, bins nt-1 (accE)
        mfmaH(accO, bbA, 0);  loadH(bbA, ptr(nt + 1), 0);  bins2(accE, 0);
        mfmaH(accO, bbB, 1);  loadH(bbB, ptr(nt + 1), 1);  bins2(accE, 2);
        zero4(accE);                                     // MFMA nt+1 -> accE, bins nt (accO)
        mfmaH(accE, bbA, 0);  loadH(bbA, ptr(nt + 2), 0);  bins2(accO, 0);
        mfmaH(accE, bbB, 1);  loadH(bbB, ptr(nt + 2), 1);  bins2(accO, 2);
    }
    // tail: bbA/bbB hold nt=63; accE holds nt=62 (unbinned)
    zero4(accO);
    mfmaH(accO, bbA, 0);  bins2(accE, 0);
    mfmaH(accO, bbB, 1);  bins2(accE, 2);
    bins2(accO, 0);
    bins2(accO, 2);
    __syncthreads();

    // epilogue, in-register per wave: rows 16w .. 16w+15
    const float binw = RANGE / (float)BINS;
    #pragma unroll
    for (int rr = 0; rr < 16; ++rr) {
        const int r = wave * 16 + rr;
        const unsigned int msk = (unsigned int)(r * 9) & 31u;
        const unsigned int* H = &hist[r * WORDS];
        // lane L holds logical words 4L..4L+3 = bins 8L..8L+7 (un-swizzle on read)
        int c[8];
        #pragma unroll
        for (int i2 = 0; i2 < 4; ++i2) {
            unsigned int wd = H[(unsigned int)(4 * lane + i2) ^ msk];
            c[2 * i2]     = (int)(wd & 0xFFFFu);
            c[2 * i2 + 1] = (int)(wd >> 16);
        }
        int local = 0;
        #pragma unroll
        for (int u = 0; u < 8; ++u) local += c[u];
        // suffix-sum over lanes
        int suf = local;
        #pragma unroll
        for (int o2 = 1; o2 < 64; o2 <<= 1) {
            int o = __shfl_down(suf, o2, 64);
            if (lane + o2 < 64) suf += o;
        }
        int run = suf - local;
        int s[8];                         // s[u] = S[8*lane + u] = #values >= bin edge
        #pragma unroll
        for (int u = 7; u >= 0; --u) { run += c[u]; s[u] = run; }

        // answer 256 queries for this row: lane handles i = qq*64 + lane
        #pragma unroll
        for (int qq = 0; qq < 4; ++qq) {
            int i = qq * 64 + lane;
            float rv = 1.0f + (float)i * (4094.0f / 255.0f);
            int k = (int)rintf(rv) + 1;   // k-th largest, k in [2, 4096]
            // binary search over lanes for last L with S[8L] >= k  (S[0]=4096>=k)
            int Lo = 0;
            #pragma unroll
            for (int st = 32; st >= 1; st >>= 1) {
                int cand = Lo + st;       // always <= 63
                int v = __shfl(s[0], cand, 64);
                if (v >= k) Lo = cand;
            }
            // within lane Lo's 8 bins: j_off = #{u: S[8Lo+u] >= k} - 1
            int j8 = 0;
            #pragma unroll
            for (int u = 0; u < 8; ++u) {
                int v = __shfl(s[u], Lo, 64);
                j8 += (v >= k) ? 1 : 0;
            }
            int j = 8 * Lo + j8 - 1;
            out[(size_t)(batch * 4096 + m0 + r) * 256 + i] = LO + ((float)j + 0.5f) * binw;
        }
    }
}

extern "C" void kernel_launch(void* const* d_in, const int* in_sizes, int n_in,
                              void* d_out, int out_size, void* d_ws, size_t ws_size,
                              hipStream_t stream) {
    const float* x = (const float*)d_in[0];
    float* out = (float*)d_out;
    const size_t nelem = (size_t)8 * 4096 * 256;          // 8,388,608
    short* xb = (short*)d_ws;
    hipLaunchKernelGGL(cvt_kernel, dim3(nelem / 1024), dim3(256), 0, stream, x, xb);
    hipLaunchKernelGGL(scpp_kernel, dim3(512), dim3(THREADS), 0, stream, xb, out);
}

// Round 8
// 202.847 us; speedup vs baseline: 2.4321x; 1.1282x over previous
//
#include <hip/hip_runtime.h>

#define THREADS 512            // 8 waves/block; 1 block/CU (128 KB LDS)
#define ROWS    128            // rows per block: B-bytes/CU halved vs ROWS=64
#define BINS    512
#define WORDS   128            // u8-packed: 4 bins per u32 word
#define LO      (-0.6f)
#define RANGE   (1.3f)

typedef short bf16x8 __attribute__((ext_vector_type(8)));
typedef float f32x4  __attribute__((ext_vector_type(4)));

// fp32 -> bf16 with round-to-nearest-even
__device__ __forceinline__ short f2bf(float f) {
    unsigned int u = __builtin_bit_cast(unsigned int, f);
    u = (u + 0x7FFFu + ((u >> 16) & 1u)) >> 16;
    return (short)u;
}

// pre-pass: fp32 X -> bf16 (one float4 per thread)
__global__ __launch_bounds__(256)
void cvt_kernel(const float* __restrict__ X, short* __restrict__ Xb) {
    int i = blockIdx.x * 256 + threadIdx.x;   // 0 .. 2097151
    float4 v = ((const float4*)X)[i];
    short4 s = { f2bf(v.x), f2bf(v.y), f2bf(v.z), f2bf(v.w) };
    ((short4*)Xb)[i] = s;
}

// B path: global_load_lds (contiguous 1KB/instr, wave-uniform LDS dest, no
// per-lane TA scatter) into a double-buffered 64-col slab; fragments read
// back via swizzled ds_read_b128. Swizzle (rule #21, both-sides): LDS byte
// (c*512 + r) stores global byte (c, r ^ ((c&7)<<4)); reads apply the same
// XOR -> bank-group = q ^ (c&7), uniform 8 lanes/group = conflict-free.
__global__ __launch_bounds__(THREADS, 2)   // 8 waves = 2/SIMD; VGPR cap 256
void scpp_kernel(const short* __restrict__ X, float* __restrict__ out) {
    extern __shared__ char smem[];          // [0,64K) hist  [64K,128K) slabs
    unsigned int* hist = (unsigned int*)smem;

    const int t    = threadIdx.x;
    const int wave = t >> 6;           // 0..7
    const int lane = t & 63;
    const int q    = lane >> 4;        // quad 0..3
    const int ln   = lane & 15;
    const int h    = wave >> 2;        // row-half: rows m0 + h*64 .. +63
    const int cg   = wave & 3;         // col-group: cols nt*64 + cg*16 .. +15
    const int bid  = blockIdx.x;       // 0..255 -> 1 block/CU, zero tail
    // XCD-batch pinning: blockIdx%8 -> XCD; batch slice resident in XCD L2.
    const int batch = bid & 7;
    const int m0    = (bid >> 3) * ROWS;
    const short* Xb = X + (size_t)batch * 4096 * 256;

    // zero histograms: 16384 words / 512 threads
    #pragma unroll
    for (int i = 0; i < (ROWS * WORDS) / THREADS; ++i)
        hist[t + THREADS * i] = 0u;

    // A fragments: 4 strips of 16 rows within this wave's row-half.
    // 128 regs -> AGPR-resident (R6 regime), cap 256 leaves room for the rest.
    bf16x8 af[4][8];
    {
        #pragma unroll
        for (int s = 0; s < 4; ++s) {
            const short* ap = Xb + (size_t)(m0 + h * 64 + s * 16 + ln) * 256 + q * 8;
            #pragma unroll
            for (int ks = 0; ks < 8; ++ks)
                af[s][ks] = *(const bf16x8*)(ap + ks * 32);
        }
        #pragma unroll
        for (int s = 0; s < 4; ++s)
            #pragma unroll
            for (int ks = 0; ks < 8; ++ks)
                asm volatile("" : "+v"(af[s][ks]));   // opaque: blocks remat
    }

    // stage one 64-col slab (32 KB) for tile nt into buffer buf.
    // 8 waves x 4 instrs x 1KB. Source pre-swizzled so linear DMA writes +
    // swizzled reads round-trip (m201 stage pattern).
    auto stage = [&](int buf, int nt) {
        char* dstb = smem + 65536 + buf * 32768;
        #pragma unroll
        for (int i = 0; i < 4; ++i) {
            int I = wave * 4 + i;                       // 1KB chunk 0..31
            int c = 2 * I + (lane >> 5);                // slab col 0..63
            int r = ((lane & 31) << 4) ^ ((c & 7) << 4);  // pre-swizzled byte
            const short* src = Xb + (size_t)(nt * 64 + c) * 256 + (r >> 1);
            __builtin_amdgcn_global_load_lds(
                (const __attribute__((address_space(1))) void*)src,
                (__attribute__((address_space(3))) void*)(dstb + I * 1024),
                16, 0, 0);
        }
    };

    stage(0, 0);
    __syncthreads();   // hist zeros + slab0 staged (barrier drains vmcnt)

    // bin transform: b = (v/256 - LO) * BINS/RANGE == v*scale + off
    const float scale = ((float)BINS / RANGE) / 256.0f;
    const float off   = -LO * ((float)BINS / RANGE);

    auto bins4 = [&](const f32x4& a, int rowbase) {
        #pragma unroll
        for (int reg = 0; reg < 4; ++reg) {
            int row = rowbase + 4 * q + reg;
            float fb = __builtin_amdgcn_fmed3f(a[reg] * scale + off, 0.0f, 511.0f);
            int b = (int)fb;
            int pw = (b >> 2) ^ ((row * 9) & 31);       // u8: word = bin>>2
            atomicAdd(&hist[row * WORDS + pw], 1u << ((b & 3) << 3));
        }
    };

    const int c  = cg * 16 + ln;       // wave's slab col for ds_read
    const int cx = (c & 7) << 4;       // read-side swizzle

    for (int nt = 0; nt < 64; ++nt) {
        char* sb = smem + 65536 + (nt & 1) * 32768;
        if (nt + 1 < 64) stage((nt + 1) & 1, nt + 1);   // issue early (T14)

        bf16x8 bb[8];
        #pragma unroll
        for (int ks = 0; ks < 8; ++ks)
            bb[ks] = *(const bf16x8*)(sb + c * 512 + ((ks * 64 + q * 16) ^ cx));

        f32x4 acc[4];
        #pragma unroll
        for (int s = 0; s < 4; ++s) acc[s] = f32x4{0.f, 0.f, 0.f, 0.f};
        __builtin_amdgcn_s_setprio(1);
        #pragma unroll
        for (int ks = 0; ks < 8; ++ks)
            #pragma unroll
            for (int s = 0; s < 4; ++s)
                acc[s] = __builtin_amdgcn_mfma_f32_16x16x32_bf16(af[s][ks], bb[ks], acc[s], 0, 0, 0);
        __builtin_amdgcn_s_setprio(0);

        #pragma unroll
        for (int s = 0; s < 4; ++s) bins4(acc[s], h * 64 + s * 16);

        __syncthreads();   // drains own stage DMAs (vmcnt0) + all reads done
    }

    // epilogue, in-register per wave: rows 16w .. 16w+15 (u8 unpack)
    const float binw = RANGE / (float)BINS;
    #pragma unroll
    for (int rr = 0; rr < 16; ++rr) {
        const int r = wave * 16 + rr;
        const unsigned int msk = (unsigned int)(r * 9) & 31u;
        const unsigned int* H = &hist[r * WORDS];
        // lane L holds logical words 2L..2L+1 = bins 8L..8L+7 (un-swizzle)
        int cnt[8];
        #pragma unroll
        for (int i2 = 0; i2 < 2; ++i2) {
            unsigned int wd = H[(unsigned int)(2 * lane + i2) ^ msk];
            cnt[4 * i2 + 0] = (int)(wd & 0xFFu);
            cnt[4 * i2 + 1] = (int)((wd >> 8)  & 0xFFu);
            cnt[4 * i2 + 2] = (int)((wd >> 16) & 0xFFu);
            cnt[4 * i2 + 3] = (int)((wd >> 24) & 0xFFu);
        }
        int local = 0;
        #pragma unroll
        for (int u = 0; u < 8; ++u) local += cnt[u];
        // suffix-sum over lanes
        int suf = local;
        #pragma unroll
        for (int o2 = 1; o2 < 64; o2 <<= 1) {
            int o = __shfl_down(suf, o2, 64);
            if (lane + o2 < 64) suf += o;
        }
        int run = suf - local;
        int s[8];                       // s[u] = S[8*lane+u] = #values >= edge
        #pragma unroll
        for (int u = 7; u >= 0; --u) { run += cnt[u]; s[u] = run; }

        // answer 256 queries for this row: lane handles i = qq*64 + lane
        #pragma unroll
        for (int qq = 0; qq < 4; ++qq) {
            int i = qq * 64 + lane;
            float rv = 1.0f + (float)i * (4094.0f / 255.0f);
            int k = (int)rintf(rv) + 1;   // k-th largest, k in [2, 4096]
            int Lo = 0;
            #pragma unroll
            for (int st = 32; st >= 1; st >>= 1) {
                int cand = Lo + st;       // always <= 63
                int v = __shfl(s[0], cand, 64);
                if (v >= k) Lo = cand;
            }
            int j8 = 0;
            #pragma unroll
            for (int u = 0; u < 8; ++u) {
                int v = __shfl(s[u], Lo, 64);
                j8 += (v >= k) ? 1 : 0;
            }
            int j = 8 * Lo + j8 - 1;
            out[(size_t)(batch * 4096 + m0 + r) * 256 + i] = LO + ((float)j + 0.5f) * binw;
        }
    }
}

extern "C" void kernel_launch(void* const* d_in, const int* in_sizes, int n_in,
                              void* d_out, int out_size, void* d_ws, size_t ws_size,
                              hipStream_t stream) {
    static int attr_set = 0;
    if (!attr_set) {   // one-time, host-side, not a stream op (capture-safe)
        hipFuncSetAttribute((const void*)scpp_kernel,
                            hipFuncAttributeMaxDynamicSharedMemorySize, 131072);
        attr_set = 1;
    }
    const float* x = (const float*)d_in[0];
    float* out = (float*)d_out;
    const size_t nelem = (size_t)8 * 4096 * 256;          // 8,388,608
    short* xb = (short*)d_ws;
    hipLaunchKernelGGL(cvt_kernel, dim3(nelem / 1024), dim3(256), 0, stream, x, xb);
    hipLaunchKernelGGL(scpp_kernel, dim3(256), dim3(THREADS), 131072, stream, xb, out);
}

// Round 9
// 190.093 us; speedup vs baseline: 2.5952x; 1.0671x over previous
//
#include <hip/hip_runtime.h>

#define THREADS 512            // 8 waves/block; 1 block/CU (128 KB LDS)
#define ROWS    128            // rows per block: B-bytes/CU halved vs ROWS=64
#define BINS    512
#define WORDS   128            // u8-packed: 4 bins per u32 word
#define LO      (-0.6f)
#define RANGE   (1.3f)

typedef short bf16x8 __attribute__((ext_vector_type(8)));
typedef float f32x4  __attribute__((ext_vector_type(4)));

// fp32 -> bf16 with round-to-nearest-even
__device__ __forceinline__ short f2bf(float f) {
    unsigned int u = __builtin_bit_cast(unsigned int, f);
    u = (u + 0x7FFFu + ((u >> 16) & 1u)) >> 16;
    return (short)u;
}

// pre-pass: fp32 X -> bf16 (one float4 per thread)
__global__ __launch_bounds__(256)
void cvt_kernel(const float* __restrict__ X, short* __restrict__ Xb) {
    int i = blockIdx.x * 256 + threadIdx.x;   // 0 .. 2097151
    float4 v = ((const float4*)X)[i];
    short4 s = { f2bf(v.x), f2bf(v.y), f2bf(v.z), f2bf(v.w) };
    ((short4*)Xb)[i] = s;
}

// B path: global_load_lds slabs + swizzled ds_read_b128 (R8, kept verbatim).
// NEW (R9): MFMA operands SWAPPED -- mfma(bb, af, acc) computes the
// transposed tile (identical numerics, operand layouts are symmetric), so
// lane ln owns ONE histogram row and an atomic instr spans 16 DISTINCT rows
// x 4 values, instead of 4 rows x 16 same-row lanes. Same-word atomic
// serialization drops ~4x; row-swizzle/pointer become loop-invariant.
__global__ __launch_bounds__(THREADS, 2)   // 8 waves = 2/SIMD; VGPR cap 256
void scpp_kernel(const short* __restrict__ X, float* __restrict__ out) {
    extern __shared__ char smem[];          // [0,64K) hist  [64K,128K) slabs
    unsigned int* hist = (unsigned int*)smem;

    const int t    = threadIdx.x;
    const int wave = t >> 6;           // 0..7
    const int lane = t & 63;
    const int q    = lane >> 4;        // quad 0..3
    const int ln   = lane & 15;
    const int h    = wave >> 2;        // row-half: rows m0 + h*64 .. +63
    const int cg   = wave & 3;         // col-group: cols nt*64 + cg*16 .. +15
    const int bid  = blockIdx.x;       // 0..255 -> 1 block/CU, zero tail
    // XCD-batch pinning: blockIdx%8 -> XCD; batch slice resident in XCD L2.
    const int batch = bid & 7;
    const int m0    = (bid >> 3) * ROWS;
    const short* Xb = X + (size_t)batch * 4096 * 256;

    // zero histograms: 16384 words / 512 threads
    #pragma unroll
    for (int i = 0; i < (ROWS * WORDS) / THREADS; ++i)
        hist[t + THREADS * i] = 0u;

    // A fragments: 4 strips of 16 rows within this wave's row-half.
    bf16x8 af[4][8];
    {
        #pragma unroll
        for (int s = 0; s < 4; ++s) {
            const short* ap = Xb + (size_t)(m0 + h * 64 + s * 16 + ln) * 256 + q * 8;
            #pragma unroll
            for (int ks = 0; ks < 8; ++ks)
                af[s][ks] = *(const bf16x8*)(ap + ks * 32);
        }
        #pragma unroll
        for (int s = 0; s < 4; ++s)
            #pragma unroll
            for (int ks = 0; ks < 8; ++ks)
                asm volatile("" : "+v"(af[s][ks]));   // opaque: blocks remat
    }

    // stage one 64-col slab (32 KB) for tile nt into buffer buf.
    auto stage = [&](int buf, int nt) {
        char* dstb = smem + 65536 + buf * 32768;
        #pragma unroll
        for (int i = 0; i < 4; ++i) {
            int I = wave * 4 + i;                       // 1KB chunk 0..31
            int c = 2 * I + (lane >> 5);                // slab col 0..63
            int r = ((lane & 31) << 4) ^ ((c & 7) << 4);  // pre-swizzled byte
            const short* src = Xb + (size_t)(nt * 64 + c) * 256 + (r >> 1);
            __builtin_amdgcn_global_load_lds(
                (const __attribute__((address_space(1))) void*)src,
                (__attribute__((address_space(3))) void*)(dstb + I * 1024),
                16, 0, 0);
        }
    };

    stage(0, 0);
    __syncthreads();   // hist zeros + slab0 staged (barrier drains vmcnt)

    // bin transform: b = (v/256 - LO) * BINS/RANGE == v*scale + off
    const float scale = ((float)BINS / RANGE) / 256.0f;
    const float off   = -LO * ((float)BINS / RANGE);

    // per-strip loop-invariant histogram row pointer + bank swizzle
    // (lane ln owns row h*64 + s*16 + ln after the operand swap)
    unsigned int* Hrow[4];
    unsigned      swzr[4];
    #pragma unroll
    for (int s = 0; s < 4; ++s) {
        int row = h * 64 + s * 16 + ln;
        Hrow[s] = &hist[row * WORDS];
        swzr[s] = (unsigned)((row * 9) & 31);
    }

    const int c  = cg * 16 + ln;       // wave's slab col for ds_read
    const int cx = (c & 7) << 4;       // read-side swizzle

    for (int nt = 0; nt < 64; ++nt) {
        char* sb = smem + 65536 + (nt & 1) * 32768;
        if (nt + 1 < 64) stage((nt + 1) & 1, nt + 1);   // issue early (T14)

        bf16x8 bb[8];
        #pragma unroll
        for (int ks = 0; ks < 8; ++ks)
            bb[ks] = *(const bf16x8*)(sb + c * 512 + ((ks * 64 + q * 16) ^ cx));

        f32x4 acc[4];
        #pragma unroll
        for (int s = 0; s < 4; ++s) acc[s] = f32x4{0.f, 0.f, 0.f, 0.f};
        __builtin_amdgcn_s_setprio(1);
        #pragma unroll
        for (int ks = 0; ks < 8; ++ks)
            #pragma unroll
            for (int s = 0; s < 4; ++s)   // SWAPPED: bb as A, af as B -> D^T
                acc[s] = __builtin_amdgcn_mfma_f32_16x16x32_bf16(bb[ks], af[s][ks], acc[s], 0, 0, 0);
        __builtin_amdgcn_s_setprio(0);

        // acc[s][reg]: row m = h*64+s*16+ln (per-lane), 4 values (n = 4q+reg)
        #pragma unroll
        for (int s = 0; s < 4; ++s) {
            #pragma unroll
            for (int reg = 0; reg < 4; ++reg) {
                float fb = __builtin_amdgcn_fmed3f(acc[s][reg] * scale + off, 0.0f, 511.0f);
                int b  = (int)fb;
                int pw = (b >> 2) ^ swzr[s];
                atomicAdd(&Hrow[s][pw], 1u << ((b & 3) << 3));
            }
        }

        __syncthreads();   // drains own stage DMAs (vmcnt0) + all reads done
    }

    // epilogue, in-register per wave: rows 16w .. 16w+15 (u8 unpack)
    const float binw = RANGE / (float)BINS;
    #pragma unroll
    for (int rr = 0; rr < 16; ++rr) {
        const int r = wave * 16 + rr;
        const unsigned int msk = (unsigned int)(r * 9) & 31u;
        const unsigned int* H = &hist[r * WORDS];
        // lane L holds logical words 2L..2L+1 = bins 8L..8L+7 (un-swizzle)
        int cnt[8];
        #pragma unroll
        for (int i2 = 0; i2 < 2; ++i2) {
            unsigned int wd = H[(unsigned int)(2 * lane + i2) ^ msk];
            cnt[4 * i2 + 0] = (int)(wd & 0xFFu);
            cnt[4 * i2 + 1] = (int)((wd >> 8)  & 0xFFu);
            cnt[4 * i2 + 2] = (int)((wd >> 16) & 0xFFu);
            cnt[4 * i2 + 3] = (int)((wd >> 24) & 0xFFu);
        }
        int local = 0;
        #pragma unroll
        for (int u = 0; u < 8; ++u) local += cnt[u];
        // suffix-sum over lanes
        int suf = local;
        #pragma unroll
        for (int o2 = 1; o2 < 64; o2 <<= 1) {
            int o = __shfl_down(suf, o2, 64);
            if (lane + o2 < 64) suf += o;
        }
        int run = suf - local;
        int s[8];                       // s[u] = S[8*lane+u] = #values >= edge
        #pragma unroll
        for (int u = 7; u >= 0; --u) { run += cnt[u]; s[u] = run; }

        // answer 256 queries for this row: lane handles i = qq*64 + lane
        #pragma unroll
        for (int qq = 0; qq < 4; ++qq) {
            int i = qq * 64 + lane;
            float rv = 1.0f + (float)i * (4094.0f / 255.0f);
            int k = (int)rintf(rv) + 1;   // k-th largest, k in [2, 4096]
            int Lo = 0;
            #pragma unroll
            for (int st = 32; st >= 1; st >>= 1) {
                int cand = Lo + st;       // always <= 63
                int v = __shfl(s[0], cand, 64);
                if (v >= k) Lo = cand;
            }
            int j8 = 0;
            #pragma unroll
            for (int u = 0; u < 8; ++u) {
                int v = __shfl(s[u], Lo, 64);
                j8 += (v >= k) ? 1 : 0;
            }
            int j = 8 * Lo + j8 - 1;
            out[(size_t)(batch * 4096 + m0 + r) * 256 + i] = LO + ((float)j + 0.5f) * binw;
        }
    }
}

extern "C" void kernel_launch(void* const* d_in, const int* in_sizes, int n_in,
                              void* d_out, int out_size, void* d_ws, size_t ws_size,
                              hipStream_t stream) {
    static int attr_set = 0;
    if (!attr_set) {   // one-time, host-side, not a stream op (capture-safe)
        hipFuncSetAttribute((const void*)scpp_kernel,
                            hipFuncAttributeMaxDynamicSharedMemorySize, 131072);
        attr_set = 1;
    }
    const float* x = (const float*)d_in[0];
    float* out = (float*)d_out;
    const size_t nelem = (size_t)8 * 4096 * 256;          // 8,388,608
    short* xb = (short*)d_ws;
    hipLaunchKernelGGL(cvt_kernel, dim3(nelem / 1024), dim3(256), 0, stream, x, xb);
    hipLaunchKernelGGL(scpp_kernel, dim3(256), dim3(THREADS), 131072, stream, xb, out);
}

// Round 10
// 189.699 us; speedup vs baseline: 2.6006x; 1.0021x over previous
//
#include <hip/hip_runtime.h>

#define THREADS 512            // 8 waves/block; 1 block/CU (128 KB LDS)
#define ROWS    128            // rows per block
#define BINS    512
#define WORDS   128            // u8-packed: 4 bins per u32 word
#define LO      (-0.6f)
#define RANGE   (1.3f)

typedef short bf16x8 __attribute__((ext_vector_type(8)));
typedef float f32x4  __attribute__((ext_vector_type(4)));

// fp32 -> bf16 with round-to-nearest-even
__device__ __forceinline__ short f2bf(float f) {
    unsigned int u = __builtin_bit_cast(unsigned int, f);
    u = (u + 0x7FFFu + ((u >> 16) & 1u)) >> 16;
    return (short)u;
}

// pre-pass: fp32 X -> bf16 (one float4 per thread)
__global__ __launch_bounds__(256)
void cvt_kernel(const float* __restrict__ X, short* __restrict__ Xb) {
    int i = blockIdx.x * 256 + threadIdx.x;   // 0 .. 2097151
    float4 v = ((const float4*)X)[i];
    short4 s = { f2bf(v.x), f2bf(v.y), f2bf(v.z), f2bf(v.w) };
    ((short4*)Xb)[i] = s;
}

// R10: BARRIER-FREE K-loop. Each wave owns a PRIVATE 8 KB slab (its 16 B-cols)
// staged by global_load_lds; sync is per-wave {vmcnt(0) -> ds_read ->
// lgkmcnt(0) -> restage}. No __syncthreads convoy, no 64x full drains; the 8
// waves anti-phase freely across MFMA/VALU/DS pipes. Cost: h=0/h=1 stage the
// same cols twice (+2 MB/CU of L2 reads, not HBM). Swizzle both-sides
// (rule #21): LDS byte (c*512+r) holds global byte (c, r ^ ((c&7)<<4)).
__global__ __launch_bounds__(THREADS, 2)   // 8 waves = 2/SIMD; VGPR cap 256
void scpp_kernel(const short* __restrict__ X, float* __restrict__ out) {
    extern __shared__ char smem[];          // [0,64K) hist  [64K,128K) slabs
    unsigned int* hist = (unsigned int*)smem;

    const int t    = threadIdx.x;
    const int wave = t >> 6;           // 0..7
    const int lane = t & 63;
    const int q    = lane >> 4;        // quad 0..3
    const int ln   = lane & 15;
    const int h    = wave >> 2;        // row-half: rows m0 + h*64 .. +63
    const int cg   = wave & 3;         // col-group: cols nt*64 + cg*16 .. +15
    const int bid  = blockIdx.x;       // 0..255 -> 1 block/CU, zero tail
    const int batch = bid & 7;         // XCD-batch pinning
    const int m0    = (bid >> 3) * ROWS;
    const short* Xb = X + (size_t)batch * 4096 * 256;

    char* slab = smem + 65536 + wave * 8192;   // private per-wave slab

    // zero histograms: 16384 words / 512 threads
    #pragma unroll
    for (int i = 0; i < (ROWS * WORDS) / THREADS; ++i)
        hist[t + THREADS * i] = 0u;

    // A fragments: 4 strips of 16 rows within this wave's row-half.
    bf16x8 af[4][8];
    {
        #pragma unroll
        for (int s = 0; s < 4; ++s) {
            const short* ap = Xb + (size_t)(m0 + h * 64 + s * 16 + ln) * 256 + q * 8;
            #pragma unroll
            for (int ks = 0; ks < 8; ++ks)
                af[s][ks] = *(const bf16x8*)(ap + ks * 32);
        }
        #pragma unroll
        for (int s = 0; s < 4; ++s)
            #pragma unroll
            for (int ks = 0; ks < 8; ++ks)
                asm volatile("" : "+v"(af[s][ks]));   // opaque: blocks remat
    }

    // stage this wave's 16 cols of tile nt into its private slab (8 x 1KB)
    auto stage = [&](int nt) {
        #pragma unroll
        for (int i = 0; i < 8; ++i) {
            int c = 2 * i + (lane >> 5);                  // slab col 0..15
            int r = ((lane & 31) << 4) ^ ((c & 7) << 4);  // pre-swizzled byte
            const short* src = Xb + (size_t)(nt * 64 + cg * 16 + c) * 256 + (r >> 1);
            __builtin_amdgcn_global_load_lds(
                (const __attribute__((address_space(1))) void*)src,
                (__attribute__((address_space(3))) void*)(slab + i * 1024),
                16, 0, 0);
        }
    };

    stage(0);
    __syncthreads();   // hist zeros visible (drains prologue vmcnt too)

    // bin transform: b = (v/256 - LO) * BINS/RANGE == v*scale + off
    const float scale = ((float)BINS / RANGE) / 256.0f;
    const float off   = -LO * ((float)BINS / RANGE);

    // loop-invariant per-strip histogram row pointer + bank swizzle
    // (lane ln owns row h*64 + s*16 + ln via the swapped-operand MFMA)
    unsigned int* Hrow[4];
    unsigned      swzr[4];
    #pragma unroll
    for (int s = 0; s < 4; ++s) {
        int row = h * 64 + s * 16 + ln;
        Hrow[s] = &hist[row * WORDS];
        swzr[s] = (unsigned)((row * 9) & 31);
    }

    const int lnx = (ln & 7) << 4;     // read-side swizzle (col = ln in slab)

    for (int nt = 0; nt < 64; ++nt) {
        asm volatile("s_waitcnt vmcnt(0)" ::: "memory");   // tile nt DMA done
        bf16x8 bb[8];
        #pragma unroll
        for (int ks = 0; ks < 8; ++ks)
            bb[ks] = *(const bf16x8*)(slab + ln * 512 + ((ks * 64 + q * 16) ^ lnx));
        asm volatile("s_waitcnt lgkmcnt(0)" ::: "memory"); // reads landed; slab free
        __builtin_amdgcn_sched_barrier(0);
        if (nt + 1 < 64) stage(nt + 1);   // DMA flight hides under MFMA+bins

        f32x4 acc[4];
        #pragma unroll
        for (int s = 0; s < 4; ++s) acc[s] = f32x4{0.f, 0.f, 0.f, 0.f};
        __builtin_amdgcn_s_setprio(1);
        #pragma unroll
        for (int ks = 0; ks < 8; ++ks)
            #pragma unroll
            for (int s = 0; s < 4; ++s)   // swapped: bb as A, af as B -> D^T
                acc[s] = __builtin_amdgcn_mfma_f32_16x16x32_bf16(bb[ks], af[s][ks], acc[s], 0, 0, 0);
        __builtin_amdgcn_s_setprio(0);

        // acc[s][reg]: row m = h*64+s*16+ln (per-lane), 4 values (n = 4q+reg)
        #pragma unroll
        for (int s = 0; s < 4; ++s) {
            #pragma unroll
            for (int reg = 0; reg < 4; ++reg) {
                float fb = __builtin_amdgcn_fmed3f(acc[s][reg] * scale + off, 0.0f, 511.0f);
                int b  = (int)fb;
                int pw = (b >> 2) ^ swzr[s];
                atomicAdd(&Hrow[s][pw], 1u << ((b & 3) << 3));
            }
        }
    }
    __syncthreads();

    // epilogue, in-register per wave: rows 16w .. 16w+15 (u8 unpack)
    const float binw = RANGE / (float)BINS;
    #pragma unroll
    for (int rr = 0; rr < 16; ++rr) {
        const int r = wave * 16 + rr;
        const unsigned int msk = (unsigned int)(r * 9) & 31u;
        const unsigned int* H = &hist[r * WORDS];
        // lane L holds logical words 2L..2L+1 = bins 8L..8L+7 (un-swizzle)
        int cnt[8];
        #pragma unroll
        for (int i2 = 0; i2 < 2; ++i2) {
            unsigned int wd = H[(unsigned int)(2 * lane + i2) ^ msk];
            cnt[4 * i2 + 0] = (int)(wd & 0xFFu);
            cnt[4 * i2 + 1] = (int)((wd >> 8)  & 0xFFu);
            cnt[4 * i2 + 2] = (int)((wd >> 16) & 0xFFu);
            cnt[4 * i2 + 3] = (int)((wd >> 24) & 0xFFu);
        }
        int local = 0;
        #pragma unroll
        for (int u = 0; u < 8; ++u) local += cnt[u];
        // suffix-sum over lanes
        int suf = local;
        #pragma unroll
        for (int o2 = 1; o2 < 64; o2 <<= 1) {
            int o = __shfl_down(suf, o2, 64);
            if (lane + o2 < 64) suf += o;
        }
        int run = suf - local;
        int s[8];                       // s[u] = S[8*lane+u] = #values >= edge
        #pragma unroll
        for (int u = 7; u >= 0; --u) { run += cnt[u]; s[u] = run; }

        // answer 256 queries for this row: lane handles i = qq*64 + lane
        #pragma unroll
        for (int qq = 0; qq < 4; ++qq) {
            int i = qq * 64 + lane;
            float rv = 1.0f + (float)i * (4094.0f / 255.0f);
            int k = (int)rintf(rv) + 1;   // k-th largest, k in [2, 4096]
            int Lo = 0;
            #pragma unroll
            for (int st = 32; st >= 1; st >>= 1) {
                int cand = Lo + st;       // always <= 63
                int v = __shfl(s[0], cand, 64);
                if (v >= k) Lo = cand;
            }
            int j8 = 0;
            #pragma unroll
            for (int u = 0; u < 8; ++u) {
                int v = __shfl(s[u], Lo, 64);
                j8 += (v >= k) ? 1 : 0;
            }
            int j = 8 * Lo + j8 - 1;
            out[(size_t)(batch * 4096 + m0 + r) * 256 + i] = LO + ((float)j + 0.5f) * binw;
        }
    }
}

extern "C" void kernel_launch(void* const* d_in, const int* in_sizes, int n_in,
                              void* d_out, int out_size, void* d_ws, size_t ws_size,
                              hipStream_t stream) {
    static int attr_set = 0;
    if (!attr_set) {   // one-time, host-side, not a stream op (capture-safe)
        hipFuncSetAttribute((const void*)scpp_kernel,
                            hipFuncAttributeMaxDynamicSharedMemorySize, 131072);
        attr_set = 1;
    }
    const float* x = (const float*)d_in[0];
    float* out = (float*)d_out;
    const size_t nelem = (size_t)8 * 4096 * 256;          // 8,388,608
    short* xb = (short*)d_ws;
    hipLaunchKernelGGL(cvt_kernel, dim3(nelem / 1024), dim3(256), 0, stream, x, xb);
    hipLaunchKernelGGL(scpp_kernel, dim3(256), dim3(THREADS), 131072, stream, xb, out);
}